// Round 13
// baseline (888.248 us; speedup 1.0000x reference)
//
#include <hip/hip_runtime.h>

typedef unsigned short u16;
typedef unsigned int   u32;
typedef __attribute__((ext_vector_type(8))) short short8;
typedef __attribute__((ext_vector_type(4))) short short4v;
typedef __attribute__((ext_vector_type(4))) float f32x4;

#define N_NODES 100000
#define NQ      128
#define DD      128
#define NE      131072
#define OO      256   // 2*D
#define NCH     391   // ceil(N_NODES/256)

__device__ __forceinline__ float b2f(u16 b){ u32 u = ((u32)b) << 16; return __uint_as_float(u); }
__device__ __forceinline__ u16 f2b(float f){ u32 u = __float_as_uint(f); u32 r = (u + 0x7FFFu + ((u >> 16) & 1u)) >> 16; return (u16)r; }
__device__ __forceinline__ float lrelu(float x){ return x > 0.0f ? x : 0.01f * x; }
__device__ __forceinline__ u32 fenc(float f){ u32 u = __float_as_uint(f); return (u & 0x80000000u) ? ~u : (u | 0x80000000u); }
__device__ __forceinline__ float fdec(u32 e){ u32 u = (e & 0x80000000u) ? (e & 0x7FFFFFFFu) : ~e; return __uint_as_float(u); }

__device__ __forceinline__ void stage4(f32x4 v, u16* dhi, u16* dlo){
  short4v h4, l4;
  #pragma unroll
  for (int i = 0; i < 4; ++i){
    u16 h = f2b(v[i]); h4[i] = (short)h; l4[i] = (short)f2b(v[i] - b2f(h));
  }
  *(short4v*)dhi = h4; *(short4v*)dlo = l4;
}

__device__ __forceinline__ void cvt4(f32x4 v, short4v& h4, short4v& l4){
  #pragma unroll
  for (int i = 0; i < 4; ++i){
    u16 h = f2b(v[i]); h4[i] = (short)h; l4[i] = (short)f2b(v[i] - b2f(h));
  }
}

// ---------------- W split: all four weights, one launch ------------------------
#define SPL_N1 (256*512)
#define SPL_N2 (256*512)
#define SPL_N3 (256*256)
#define SPL_N4 (128*128)
__global__ void split_all_kernel(
    const float* __restrict__ Wl, const float* __restrict__ Wr,
    const float* __restrict__ Wc, const float* __restrict__ Ws,
    u16* __restrict__ WlH, u16* __restrict__ WlL,
    u16* __restrict__ WrH, u16* __restrict__ WrL,
    u16* __restrict__ WcH, u16* __restrict__ WcL,
    u16* __restrict__ WsH, u16* __restrict__ WsL)
{
  int i = blockIdx.x*256 + threadIdx.x;
  const float* src; u16 *hi, *lo; int k = i;
  if (k < SPL_N1){ src = Wl; hi = WlH; lo = WlL; }
  else if ((k -= SPL_N1) < SPL_N2){ src = Wr; hi = WrH; lo = WrL; }
  else if ((k -= SPL_N2) < SPL_N3){ src = Wc; hi = WcH; lo = WcL; }
  else if ((k -= SPL_N3) < SPL_N4){ src = Ws; hi = WsH; lo = WsL; }
  else return;
  float x = src[k];
  u16 h = f2b(x);
  hi[k] = h;
  lo[k] = f2b(x - b2f(h));
}

// ---------------- K0: per-query tables (exact f32, LDS-tiled coalesced W) -------
__global__ __launch_bounds__(256) void qtable_kernel(
    const float* __restrict__ qsrc, const float* __restrict__ qrel,
    const float* __restrict__ Wl, const float* __restrict__ bl,
    const float* __restrict__ Wr, const float* __restrict__ br,
    float* __restrict__ Qlt, float* __restrict__ Qrt)
{
  int b = blockIdx.x; int side = b >> 7; int q = b & 127; int o = threadIdx.x;
  __shared__ __align__(16) float s[2*DD];
  __shared__ float sW[256*17];
  if (o < DD) s[o] = qsrc[q*DD + o];
  else        s[o] = qrel[q*DD + o - DD];
  const float* W    = side ? Wr : Wl;
  const float* bias = side ? br : bl;
  float acc = bias[o];
  for (int kt = 0; kt < 16; ++kt){
    __syncthreads();                       // prev tile fully consumed
    for (int f = o; f < 4096; f += 256){   // coalesced: 4 rows x 64B per wave
      int oo = f >> 4, kk = f & 15;
      sW[oo*17 + kk] = W[(size_t)oo*512 + 256 + kt*16 + kk];
    }
    __syncthreads();
    #pragma unroll
    for (int kk = 0; kk < 16; ++kk)
      acc += s[kt*16 + kk] * sW[o*17 + kk];
  }
  (side ? Qrt : Qlt)[q*OO + o] = acc;
}

// ---------------- K1: fused edge bilinear -> logits (hi/lo 3-term MFMA) -------
// Frozen at measured-best structure (284-293 us across R4/R9/R11; three
// latency-hiding restructures all null -> structural ceiling at 2 blocks/CU).
#define BM   64
#define RSTc 264
#define HST  136

template<int WS>
__device__ __forceinline__ void gemm8(f32x4 (&ACC)[4][2],
    const u16* __restrict__ WH, const u16* __restrict__ WL,
    const u16* A0H, const u16* A0L, const u16* A1H, const u16* A1L, int ASTR,
    int ow, int ln, int qd)
{
  short8 pbh[2][2], pbl[2][2];   // [slot][nt] — 2-deep ring
  #pragma unroll
  for (int d = 0; d < 2; ++d)
    #pragma unroll
    for (int nt = 0; nt < 2; ++nt){ int o = ow + nt*16 + ln;
      pbh[d][nt] = *(const short8*)(WH + (size_t)o*WS + d*32 + qd*8);
      pbl[d][nt] = *(const short8*)(WL + (size_t)o*WS + d*32 + qd*8);
    }
  #pragma unroll
  for (int c = 0; c < 8; ++c){
    const u16* hs = (c < 4) ? A0H : A1H;
    const u16* ls = (c < 4) ? A0L : A1L;
    int cc = (c < 4) ? c : c - 4;
    short8 bh[2], bl[2];
    #pragma unroll
    for (int nt = 0; nt < 2; ++nt){ bh[nt] = pbh[c&1][nt]; bl[nt] = pbl[c&1][nt]; }
    if (c < 6){
      #pragma unroll
      for (int nt = 0; nt < 2; ++nt){ int o = ow + nt*16 + ln;
        pbh[c&1][nt] = *(const short8*)(WH + (size_t)o*WS + (c+2)*32 + qd*8);
        pbl[c&1][nt] = *(const short8*)(WL + (size_t)o*WS + (c+2)*32 + qd*8);
      }
    }
    #pragma unroll
    for (int mp = 0; mp < 2; ++mp){        // mt pairs {0,1},{2,3}
      short8 ah[2], al[2];
      #pragma unroll
      for (int k = 0; k < 2; ++k){
        int base = ((mp*2 + k)*16 + ln)*ASTR + cc*32 + qd*8;
        ah[k] = *(const short8*)&hs[base];
        al[k] = *(const short8*)&ls[base];
      }
      #pragma unroll
      for (int k = 0; k < 2; ++k)
        #pragma unroll
        for (int nt = 0; nt < 2; ++nt)
          ACC[mp*2+k][nt] = __builtin_amdgcn_mfma_f32_16x16x32_bf16(ah[k], bh[nt], ACC[mp*2+k][nt], 0, 0, 0);
      #pragma unroll
      for (int k = 0; k < 2; ++k)
        #pragma unroll
        for (int nt = 0; nt < 2; ++nt)
          ACC[mp*2+k][nt] = __builtin_amdgcn_mfma_f32_16x16x32_bf16(ah[k], bl[nt], ACC[mp*2+k][nt], 0, 0, 0);
      #pragma unroll
      for (int k = 0; k < 2; ++k)
        #pragma unroll
        for (int nt = 0; nt < 2; ++nt)
          ACC[mp*2+k][nt] = __builtin_amdgcn_mfma_f32_16x16x32_bf16(al[k], bh[nt], ACC[mp*2+k][nt], 0, 0, 0);
    }
  }
}

__global__ __launch_bounds__(512, 4) void edge_logits_kernel(
    const float* __restrict__ node_rep, const float* __restrict__ rel_emb,
    const u16* __restrict__ WlH, const u16* __restrict__ WlL,
    const u16* __restrict__ WrH, const u16* __restrict__ WrL,
    const u16* __restrict__ WcH, const u16* __restrict__ WcL,
    const float* __restrict__ bcb,
    const float* __restrict__ Qlt, const float* __restrict__ Qrt,
    const int* __restrict__ idx_i, const int* __restrict__ idx_j, const int* __restrict__ qidx,
    float* __restrict__ logits, u32* __restrict__ segmax, int* __restrict__ qcount)
{
  __shared__ __align__(16) u16 bufA[2*BM*HST];  // Hj -> Hi -> RRhi
  __shared__ __align__(16) u16 bufB[2*BM*HST];  // Rel -> RRlo
  __shared__ int qidS[BM];
  __shared__ float lpart[8][BM];

  u16* HjHi = bufA;  u16* HjLo = bufA + BM*HST;
  u16* ReHi = bufB;  u16* ReLo = bufB + BM*HST;
  u16* RRhi = bufA;  u16* RRlo = bufB;

  const int tid = threadIdx.x;
  const int e0 = blockIdx.x * BM;
  const int lane = tid & 63, w = tid >> 6;
  const int ln = lane & 15, qd = lane >> 4;
  const int ow = w * 32;

  if (tid < BM) qidS[tid] = qidx[e0 + tid];

  #pragma unroll
  for (int it = 0; it < 4; ++it){
    int c = tid + it*512;
    int r = c >> 5, seg = (c & 31) << 2;
    int j = idx_j[e0 + r];
    f32x4 vj = *(const f32x4*)(node_rep + (size_t)j*DD + seg);
    f32x4 vr = *(const f32x4*)(rel_emb + (size_t)(e0 + r)*DD + seg);
    stage4(vj, &HjHi[r*HST + seg], &HjLo[r*HST + seg]);
    stage4(vr, &ReHi[r*HST + seg], &ReLo[r*HST + seg]);
  }
  short4v hpreH[4], hpreL[4];
  #pragma unroll
  for (int it = 0; it < 4; ++it){
    int c = tid + it*512;
    int r = c >> 5, seg = (c & 31) << 2;
    f32x4 v = *(const f32x4*)(node_rep + (size_t)idx_i[e0 + r]*DD + seg);
    cvt4(v, hpreH[it], hpreL[it]);
  }
  __syncthreads();

  f32x4 acc[4][2];
  #pragma unroll
  for (int mt = 0; mt < 4; ++mt)
    #pragma unroll
    for (int nt = 0; nt < 2; ++nt) acc[mt][nt] = (f32x4){0.f,0.f,0.f,0.f};
  gemm8<512>(acc, WrH, WrL, HjHi, HjLo, ReHi, ReLo, HST, ow, ln, qd);
  __syncthreads();

  #pragma unroll
  for (int it = 0; it < 4; ++it){
    int c = tid + it*512;
    int r = c >> 5, seg = (c & 31) << 2;
    *(short4v*)&HjHi[r*HST + seg] = hpreH[it];
    *(short4v*)&HjLo[r*HST + seg] = hpreL[it];
  }
  __syncthreads();

  f32x4 lacc[4][2];
  #pragma unroll
  for (int mt = 0; mt < 4; ++mt)
    #pragma unroll
    for (int nt = 0; nt < 2; ++nt) lacc[mt][nt] = (f32x4){0.f,0.f,0.f,0.f};
  gemm8<512>(lacc, WlH, WlL, HjHi, HjLo, ReHi, ReLo, HST, ow, ln, qd);
  __syncthreads();

  #pragma unroll
  for (int mt = 0; mt < 4; ++mt)
    #pragma unroll
    for (int nt = 0; nt < 2; ++nt){
      int col = ow + nt*16 + ln;
      #pragma unroll
      for (int rg = 0; rg < 4; ++rg){
        int row = mt*16 + qd*4 + rg;
        float v = acc[mt][nt][rg] + Qrt[qidS[row]*OO + col];
        v = lrelu(v);
        u16 hi = f2b(v);
        RRhi[row*RSTc + col] = hi;
        RRlo[row*RSTc + col] = f2b(v - b2f(hi));
      }
    }
  __syncthreads();

  f32x4 racc[4][2];
  #pragma unroll
  for (int mt = 0; mt < 4; ++mt)
    #pragma unroll
    for (int nt = 0; nt < 2; ++nt) racc[mt][nt] = (f32x4){0.f,0.f,0.f,0.f};
  gemm8<256>(racc, WcH, WcL, RRhi, RRlo, RRhi + 128, RRlo + 128, RSTc, ow, ln, qd);

  float bcv[2];
  #pragma unroll
  for (int nt = 0; nt < 2; ++nt) bcv[nt] = bcb[ow + nt*16 + ln];

  float part[4][4];
  #pragma unroll
  for (int mt = 0; mt < 4; ++mt)
    #pragma unroll
    for (int rg = 0; rg < 4; ++rg) part[mt][rg] = 0.f;

  #pragma unroll
  for (int mt = 0; mt < 4; ++mt)
    #pragma unroll
    for (int nt = 0; nt < 2; ++nt){
      int col = ow + nt*16 + ln;
      #pragma unroll
      for (int rg = 0; rg < 4; ++rg){
        int row = mt*16 + qd*4 + rg;
        float lv = lacc[mt][nt][rg] + Qlt[qidS[row]*OO + col];
        lv = lrelu(lv);
        float rv = racc[mt][nt][rg] + bcv[nt];
        part[mt][rg] += lv * rv;
      }
    }

  #pragma unroll
  for (int mt = 0; mt < 4; ++mt)
    #pragma unroll
    for (int rg = 0; rg < 4; ++rg){
      float p = part[mt][rg];
      p += __shfl_xor(p, 1); p += __shfl_xor(p, 2);
      p += __shfl_xor(p, 4); p += __shfl_xor(p, 8);
      if (ln == 0) lpart[w][mt*16 + qd*4 + rg] = p;
    }
  __syncthreads();
  if (tid < BM){
    float lg = lpart[0][tid] + lpart[1][tid] + lpart[2][tid] + lpart[3][tid]
             + lpart[4][tid] + lpart[5][tid] + lpart[6][tid] + lpart[7][tid];
    int e = e0 + tid;
    logits[e] = lg;
    atomicMax(segmax + idx_i[e], fenc(lg));   // fused seg_max_count
    atomicAdd(qcount + qidx[e], 1);
  }
}

// ---------------- K2: segment exp + denom sum (+ per-target-node count) --------
__global__ void seg_exp_sum_kernel(const float* __restrict__ logits,
    const int* __restrict__ idx_i, const int* __restrict__ idx_j,
    const u32* __restrict__ segmax,
    float* __restrict__ ex, float* __restrict__ denom, int* __restrict__ jcount)
{
  int e = blockIdx.x*256 + threadIdx.x; if (e >= NE) return;
  int i = idx_i[e];
  float d = fminf(logits[e] - fdec(segmax[i]), 0.0f);
  float v = expf(d);
  ex[e] = v;
  atomicAdd(denom + i, v);
  atomicAdd(jcount + idx_j[e], 1);          // count ALL edges per target node
}

// ---------------- K3: scan of query counts (wave-parallel Hillis-Steele) -------
__global__ __launch_bounds__(128) void scan_kernel(const int* __restrict__ qcount,
                            int* __restrict__ qstart, int* __restrict__ qcursor)
{
  __shared__ int s[NQ];
  int t = threadIdx.x;
  int mine = qcount[t];
  s[t] = mine;
  __syncthreads();
  #pragma unroll
  for (int off = 1; off < NQ; off <<= 1){
    int v = (t >= off) ? s[t - off] : 0;
    __syncthreads();
    s[t] += v;
    __syncthreads();
  }
  int excl = s[t] - mine;
  qstart[t] = excl;
  qcursor[t] = excl;
}

// ---------------- K3b/c/d: 2-level scan of per-node edge counts ---------------
__global__ __launch_bounds__(256) void jscan_a(const int* __restrict__ jcount,
                                               int* __restrict__ csum)
{
  __shared__ int s[256];
  int b = blockIdx.x, t = threadIdx.x;
  int i = b*256 + t;
  s[t] = (i < N_NODES) ? jcount[i] : 0;
  __syncthreads();
  #pragma unroll
  for (int off = 128; off > 0; off >>= 1){
    if (t < off) s[t] += s[t + off];
    __syncthreads();
  }
  if (t == 0) csum[b] = s[0];
}

__global__ __launch_bounds__(512) void jscan_b(const int* __restrict__ csum,
                                               int* __restrict__ coff,
                                               int* __restrict__ jstart)
{
  __shared__ int s[512];
  int t = threadIdx.x;
  int v = (t < NCH) ? csum[t] : 0;
  s[t] = v;
  __syncthreads();
  #pragma unroll
  for (int off = 1; off < 512; off <<= 1){
    int u = (t >= off) ? s[t - off] : 0;
    __syncthreads();
    s[t] += u;
    __syncthreads();
  }
  if (t < NCH) coff[t] = s[t] - v;   // exclusive prefix of chunk sums
  if (t == 0) jstart[N_NODES] = NE;
}

__global__ __launch_bounds__(256) void jscan_c(const int* __restrict__ jcount,
    const int* __restrict__ coff, int* __restrict__ jstart, int* __restrict__ jcursor)
{
  __shared__ int s[256];
  int b = blockIdx.x, t = threadIdx.x;
  int i = b*256 + t;
  int mine = (i < N_NODES) ? jcount[i] : 0;
  s[t] = mine;
  __syncthreads();
  #pragma unroll
  for (int off = 1; off < 256; off <<= 1){
    int u = (t >= off) ? s[t - off] : 0;
    __syncthreads();
    s[t] += u;
    __syncthreads();
  }
  if (i < N_NODES){
    int excl = coff[b] + s[t] - mine;
    jstart[i] = excl;
    jcursor[i] = excl;
  }
}

// ---------------- K4: fused attn/target + q-bucket + j-bucket fill -------------
__global__ void attn_bucket_kernel(const float* __restrict__ ex,
    const float* __restrict__ denom, const int* __restrict__ idx_i,
    const int* __restrict__ idx_j,
    const float* __restrict__ visited, const int* __restrict__ qidx,
    int* __restrict__ qcursor, int* __restrict__ bucket,
    int* __restrict__ jcursor, int* __restrict__ jbucket,
    float* __restrict__ attn, float* __restrict__ target)
{
  int e = blockIdx.x*256 + threadIdx.x; if (e >= NE) return;
  int i = idx_i[e];
  float a = ex[e] / fmaxf(denom[i], 1e-30f);
  attn[e] = a;
  target[e] = a * visited[i];
  int p = atomicAdd(qcursor + qidx[e], 1);
  bucket[p] = e;
  int p2 = atomicAdd(jcursor + idx_j[e], 1);
  jbucket[p2] = e;
}

// ---------------- K5: exact per-group top-k (count-beats, lexsort-stable) ------
#define TOPK_CAP 2560
__global__ __launch_bounds__(1024) void topk_kernel(
    const int* __restrict__ qcount, const int* __restrict__ qstart,
    const int* __restrict__ bucket, const float* __restrict__ target,
    const int* __restrict__ maxe_p, int* __restrict__ keep)
{
  __shared__ float ss[TOPK_CAP];
  __shared__ int   se[TOPK_CAP];
  int q = blockIdx.x;
  int m = qcount[q], start = qstart[q];
  int maxe = *maxe_p;
  if (maxe <= 0 || maxe > (1 << 30)){
    float f = __int_as_float(maxe);
    if (f > 0.0f && f < 1.0e9f) maxe = (int)f;
  }
  int tid = threadIdx.x;
  if (m <= maxe){
    for (int i = tid; i < m; i += 1024) keep[bucket[start + i]] = 1;
    return;
  }
  if (m <= TOPK_CAP){
    for (int i = tid; i < m; i += 1024){
      int e = bucket[start + i]; ss[i] = target[e]; se[i] = e;
    }
    __syncthreads();
    for (int i = tid; i < m; i += 1024){
      float s = ss[i]; int eid = se[i]; int cnt = 0;
      for (int j = 0; j < m; ++j){
        float sj = ss[j]; int ej = se[j];
        cnt += (sj > s) || (sj == s && ej < eid);
      }
      keep[eid] = (cnt < maxe) ? 1 : 0;
    }
  } else {
    for (int i = tid; i < m; i += 1024){
      int eid = bucket[start + i]; float s = target[eid]; int cnt = 0;
      for (int j = 0; j < m; ++j){
        int ej = bucket[start + j]; float sj = target[ej];
        cnt += (sj > s) || (sj == s && ej < eid);
      }
      keep[eid] = (cnt < maxe) ? 1 : 0;
    }
  }
}

// ---------------- K6: fused per-node aggregate + step GEMM --------------------
// Replaces edge_scatter (30.7M global lane-atomics) + final_mfma. Edges are
// j-sorted (jstart/jbucket); each block owns 64 target nodes, accumulates
// attn*hi into an f32 LDS tile with LDS atomics, scores into LDS scalars
// (out_score becomes a plain store), then MFMAs with on-the-fly bf16 hi/lo
// fragment conversion. Zero global atomics; d_out memset eliminated.
#define PADF 132
__global__ __launch_bounds__(256) void final_fused_kernel(
    const float* __restrict__ node_rep,
    const int* __restrict__ jstart, const int* __restrict__ jbucket,
    const int* __restrict__ keep, const float* __restrict__ attn,
    const float* __restrict__ target,
    const int* __restrict__ idx_i, const int* __restrict__ idx_j,
    const u16* __restrict__ WsH, const u16* __restrict__ WsL,
    const float* __restrict__ bstep,
    float* __restrict__ out_score, float* __restrict__ out_rep)
{
  __shared__ __align__(16) float Af[64*PADF];
  __shared__ float scoreS[64];
  const int tid = threadIdx.x;
  const int m0 = blockIdx.x * 64;
  const int lane = tid & 63, wv = tid >> 6;

  // init Af with node_rep rows (zero-pad past N), scoreS with 0
  for (int c = tid; c < 64*32; c += 256){
    int r = c >> 5, seg = (c & 31) << 2;
    int m = m0 + r;
    f32x4 v = (m < N_NODES) ? *(const f32x4*)(node_rep + (size_t)m*DD + seg)
                            : (f32x4){0.f,0.f,0.f,0.f};
    *(f32x4*)&Af[r*PADF + seg] = v;
  }
  if (tid < 64) scoreS[tid] = 0.f;
  __syncthreads();

  // accumulate kept incident edges (one wave per edge, LDS atomics)
  int lo = jstart[m0];
  int hi = jstart[(m0 + 64 < N_NODES) ? (m0 + 64) : N_NODES];
  for (int p = lo + wv; p < hi; p += 4){
    int e = jbucket[p];
    if (!keep[e]) continue;                 // wave-uniform
    int ii = idx_i[e];
    float a = attn[e];
    int row = idx_j[e] - m0;
    float h0 = node_rep[(size_t)ii*DD + lane];
    float h1 = node_rep[(size_t)ii*DD + 64 + lane];
    atomicAdd(&Af[row*PADF + lane],      a*h0);
    atomicAdd(&Af[row*PADF + 64 + lane], a*h1);
    if (lane == 0) atomicAdd(&scoreS[row], target[e]);
  }
  __syncthreads();

  if (tid < 64 && m0 + tid < N_NODES) out_score[m0 + tid] = scoreS[tid];

  // step GEMM: fragments converted on the fly from Af (f32 LDS)
  const int ln = lane & 15, qd = lane >> 4;
  const int ow = wv * 32;

  short8 bh[2][4], bl[2][4];
  #pragma unroll
  for (int nt = 0; nt < 2; ++nt)
    #pragma unroll
    for (int c = 0; c < 4; ++c){
      int o = ow + nt*16 + ln;
      bh[nt][c] = *(const short8*)(WsH + (size_t)o*DD + c*32 + qd*8);
      bl[nt][c] = *(const short8*)(WsL + (size_t)o*DD + c*32 + qd*8);
    }

  f32x4 acc[4][2];
  #pragma unroll
  for (int mt = 0; mt < 4; ++mt)
    #pragma unroll
    for (int nt = 0; nt < 2; ++nt) acc[mt][nt] = (f32x4){0.f,0.f,0.f,0.f};

  #pragma unroll
  for (int mt = 0; mt < 4; ++mt)
    #pragma unroll
    for (int c = 0; c < 4; ++c){
      const float* ap = &Af[(mt*16 + ln)*PADF + c*32 + qd*8];
      f32x4 a0 = *(const f32x4*)ap;
      f32x4 a1 = *(const f32x4*)(ap + 4);
      short8 ah, al;
      #pragma unroll
      for (int i = 0; i < 4; ++i){
        u16 h = f2b(a0[i]); ah[i] = (short)h; al[i] = (short)f2b(a0[i] - b2f(h));
      }
      #pragma unroll
      for (int i = 0; i < 4; ++i){
        u16 h = f2b(a1[i]); ah[4+i] = (short)h; al[4+i] = (short)f2b(a1[i] - b2f(h));
      }
      #pragma unroll
      for (int nt = 0; nt < 2; ++nt){
        acc[mt][nt] = __builtin_amdgcn_mfma_f32_16x16x32_bf16(ah, bh[nt][c], acc[mt][nt], 0, 0, 0);
        acc[mt][nt] = __builtin_amdgcn_mfma_f32_16x16x32_bf16(ah, bl[nt][c], acc[mt][nt], 0, 0, 0);
        acc[mt][nt] = __builtin_amdgcn_mfma_f32_16x16x32_bf16(al, bh[nt][c], acc[mt][nt], 0, 0, 0);
      }
    }

  #pragma unroll
  for (int mt = 0; mt < 4; ++mt)
    #pragma unroll
    for (int nt = 0; nt < 2; ++nt){
      int col = ow + nt*16 + ln;
      float bs = bstep[col];
      #pragma unroll
      for (int rg = 0; rg < 4; ++rg){
        int m = m0 + mt*16 + qd*4 + rg;
        if (m < N_NODES)
          out_rep[(size_t)m*DD + col] = lrelu(acc[mt][nt][rg] + bs);
      }
    }
}

// ---------------- host ---------------------------------------------------------
extern "C" void kernel_launch(void* const* d_in, const int* in_sizes, int n_in,
                              void* d_out, int out_size, void* d_ws, size_t ws_size,
                              hipStream_t stream)
{
  const float* visited  = (const float*)d_in[0];
  const float* node_rep = (const float*)d_in[1];
  const float* qsrc     = (const float*)d_in[2];
  const float* qrel     = (const float*)d_in[3];
  const float* rel_emb  = (const float*)d_in[4];
  const float* Wl       = (const float*)d_in[5];
  const float* bl       = (const float*)d_in[6];
  const float* Wr       = (const float*)d_in[7];
  const float* br       = (const float*)d_in[8];
  const float* Wc       = (const float*)d_in[9];
  const float* bcb      = (const float*)d_in[10];
  const float* Wstep    = (const float*)d_in[11];
  const float* bstep    = (const float*)d_in[12];
  const int* qidx       = (const int*)d_in[13];
  const int* idx_i      = (const int*)d_in[14];
  const int* idx_j      = (const int*)d_in[15];
  const int* maxe       = (const int*)d_in[16];

  char* wp = (char*)d_ws;
  size_t used = 0;
  auto alloc = [&](size_t bytes)->char*{
    size_t pad = (bytes + 255) & ~(size_t)255;
    char* p = wp + used; used += pad; return p;
  };
  float* Qlt    = (float*)alloc((size_t)NQ*OO*4);
  float* Qrt    = (float*)alloc((size_t)NQ*OO*4);
  float* logits = (float*)alloc((size_t)NE*4);
  float* ex     = (float*)alloc((size_t)NE*4);
  float* attn   = (float*)alloc((size_t)NE*4);
  float* target = (float*)alloc((size_t)NE*4);
  u32*   segmax = (u32*)  alloc((size_t)N_NODES*4);
  float* denom  = (float*)alloc((size_t)N_NODES*4);
  int*   qcount = (int*)  alloc((size_t)NQ*4);
  int*   qstart = (int*)  alloc((size_t)NQ*4);
  int*   qcursor= (int*)  alloc((size_t)NQ*4);
  int*   bucket = (int*)  alloc((size_t)NE*4);
  int*   keep   = (int*)  alloc((size_t)NE*4);
  int*   jcount = (int*)  alloc((size_t)N_NODES*4);
  int*   jstart = (int*)  alloc(((size_t)N_NODES + 1)*4);
  int*   jcursor= (int*)  alloc((size_t)N_NODES*4);
  int*   jbucket= (int*)  alloc((size_t)NE*4);
  int*   csum   = (int*)  alloc((size_t)NCH*4);
  int*   coff   = (int*)  alloc((size_t)NCH*4);
  u16* WlH = (u16*)alloc((size_t)256*512*2); u16* WlL = (u16*)alloc((size_t)256*512*2);
  u16* WrH = (u16*)alloc((size_t)256*512*2); u16* WrL = (u16*)alloc((size_t)256*512*2);
  u16* WcH = (u16*)alloc((size_t)256*256*2); u16* WcL = (u16*)alloc((size_t)256*256*2);
  u16* WsH = (u16*)alloc((size_t)128*128*2); u16* WsL = (u16*)alloc((size_t)128*128*2);
  (void)ws_size; (void)in_sizes; (void)n_in; (void)out_size;

  float* out_score = (float*)d_out;               // f32 outputs (fully written)
  float* out_rep   = (float*)d_out + N_NODES;     // fully written by final_fused

  hipMemsetAsync(segmax, 0, (size_t)N_NODES*4, stream);
  hipMemsetAsync(denom,  0, (size_t)N_NODES*4, stream);
  hipMemsetAsync(jcount, 0, (size_t)N_NODES*4, stream);
  hipMemsetAsync(qcount, 0, (size_t)NQ*4,      stream);
  hipMemsetAsync(keep,   0, (size_t)NE*4,      stream);

  {
    int n_all = SPL_N1 + SPL_N2 + SPL_N3 + SPL_N4;
    split_all_kernel<<<(n_all + 255)/256, 256, 0, stream>>>(Wl, Wr, Wc, Wstep,
        WlH, WlL, WrH, WrL, WcH, WcL, WsH, WsL);
  }

  qtable_kernel<<<256, 256, 0, stream>>>(qsrc, qrel, Wl, bl, Wr, br, Qlt, Qrt);

  edge_logits_kernel<<<NE/BM, 512, 0, stream>>>(node_rep, rel_emb,
      WlH, WlL, WrH, WrL, WcH, WcL, bcb, Qlt, Qrt, idx_i, idx_j, qidx,
      logits, segmax, qcount);

  seg_exp_sum_kernel<<<NE/256, 256, 0, stream>>>(logits, idx_i, idx_j, segmax,
                                                 ex, denom, jcount);
  scan_kernel<<<1, 128, 0, stream>>>(qcount, qstart, qcursor);
  jscan_a<<<NCH, 256, 0, stream>>>(jcount, csum);
  jscan_b<<<1, 512, 0, stream>>>(csum, coff, jstart);
  jscan_c<<<NCH, 256, 0, stream>>>(jcount, coff, jstart, jcursor);

  attn_bucket_kernel<<<NE/256, 256, 0, stream>>>(ex, denom, idx_i, idx_j,
                                                 visited, qidx, qcursor, bucket,
                                                 jcursor, jbucket, attn, target);
  topk_kernel<<<NQ, 1024, 0, stream>>>(qcount, qstart, bucket, target, maxe, keep);

  final_fused_kernel<<<(N_NODES + 63)/64, 256, 0, stream>>>(node_rep,
      jstart, jbucket, keep, attn, target, idx_i, idx_j,
      WsH, WsL, bstep, out_score, out_rep);
}

// Round 15
// 842.712 us; speedup vs baseline: 1.0540x; 1.0540x over previous
//
#include <hip/hip_runtime.h>

typedef unsigned short u16;
typedef unsigned int   u32;
typedef __attribute__((ext_vector_type(8))) short short8;
typedef __attribute__((ext_vector_type(4))) short short4v;
typedef __attribute__((ext_vector_type(4))) float f32x4;

#define N_NODES 100000
#define NQ      128
#define DD      128
#define NE      131072
#define OO      256   // 2*D

__device__ __forceinline__ float b2f(u16 b){ u32 u = ((u32)b) << 16; return __uint_as_float(u); }
__device__ __forceinline__ u16 f2b(float f){ u32 u = __float_as_uint(f); u32 r = (u + 0x7FFFu + ((u >> 16) & 1u)) >> 16; return (u16)r; }
__device__ __forceinline__ float lrelu(float x){ return x > 0.0f ? x : 0.01f * x; }
__device__ __forceinline__ u32 fenc(float f){ u32 u = __float_as_uint(f); return (u & 0x80000000u) ? ~u : (u | 0x80000000u); }
__device__ __forceinline__ float fdec(u32 e){ u32 u = (e & 0x80000000u) ? (e & 0x7FFFFFFFu) : ~e; return __uint_as_float(u); }

__device__ __forceinline__ void stage4(f32x4 v, u16* dhi, u16* dlo){
  short4v h4, l4;
  #pragma unroll
  for (int i = 0; i < 4; ++i){
    u16 h = f2b(v[i]); h4[i] = (short)h; l4[i] = (short)f2b(v[i] - b2f(h));
  }
  *(short4v*)dhi = h4; *(short4v*)dlo = l4;
}

__device__ __forceinline__ void cvt4(f32x4 v, short4v& h4, short4v& l4){
  #pragma unroll
  for (int i = 0; i < 4; ++i){
    u16 h = f2b(v[i]); h4[i] = (short)h; l4[i] = (short)f2b(v[i] - b2f(h));
  }
}

// ---------------- W split: all four weights, one launch ------------------------
#define SPL_N1 (256*512)
#define SPL_N2 (256*512)
#define SPL_N3 (256*256)
#define SPL_N4 (128*128)
__global__ void split_all_kernel(
    const float* __restrict__ Wl, const float* __restrict__ Wr,
    const float* __restrict__ Wc, const float* __restrict__ Ws,
    u16* __restrict__ WlH, u16* __restrict__ WlL,
    u16* __restrict__ WrH, u16* __restrict__ WrL,
    u16* __restrict__ WcH, u16* __restrict__ WcL,
    u16* __restrict__ WsH, u16* __restrict__ WsL)
{
  int i = blockIdx.x*256 + threadIdx.x;
  const float* src; u16 *hi, *lo; int k = i;
  if (k < SPL_N1){ src = Wl; hi = WlH; lo = WlL; }
  else if ((k -= SPL_N1) < SPL_N2){ src = Wr; hi = WrH; lo = WrL; }
  else if ((k -= SPL_N2) < SPL_N3){ src = Wc; hi = WcH; lo = WcL; }
  else if ((k -= SPL_N3) < SPL_N4){ src = Ws; hi = WsH; lo = WsL; }
  else return;
  float x = src[k];
  u16 h = f2b(x);
  hi[k] = h;
  lo[k] = f2b(x - b2f(h));
}

// ---------------- K0: per-query tables (exact f32) ----------------------------
__global__ __launch_bounds__(256) void qtable_kernel(
    const float* __restrict__ qsrc, const float* __restrict__ qrel,
    const float* __restrict__ Wl, const float* __restrict__ bl,
    const float* __restrict__ Wr, const float* __restrict__ br,
    float* __restrict__ Qlt, float* __restrict__ Qrt)
{
  int b = blockIdx.x; int side = b >> 7; int q = b & 127; int o = threadIdx.x;
  __shared__ __align__(16) float s[2*DD];
  if (threadIdx.x < DD) s[threadIdx.x] = qsrc[q*DD + threadIdx.x];
  else                  s[threadIdx.x] = qrel[q*DD + threadIdx.x - DD];
  __syncthreads();
  const float* W    = side ? Wr : Wl;
  const float* bias = side ? br : bl;
  float acc = bias[o];
  const float* wrow = W + (size_t)o*512 + 256;
  #pragma unroll 4
  for (int k4 = 0; k4 < 64; ++k4){
    f32x4 wv = *(const f32x4*)(wrow + k4*4);
    f32x4 sv = *(const f32x4*)(s + k4*4);
    acc += sv[0]*wv[0]; acc += sv[1]*wv[1]; acc += sv[2]*wv[2]; acc += sv[3]*wv[3];
  }
  (side ? Qrt : Qlt)[q*OO + o] = acc;
}

// ---------------- K1: fused edge bilinear -> logits (hi/lo 3-term MFMA) -------
// Session-best measured config (R9: 839.66 us total, edge_logits 290 us):
// BM=64, 512 threads, 2 blocks/CU. 1-deep weight prefetch both GEMMs;
// Hi pre-gathered + converted at gather time. Term-major MFMA order ->
// bit-identical numerics. Three further latency restructures measured null.
#define BM   64
#define RSTc 264
#define HST  136

template<int WS, int PF>
__device__ __forceinline__ void gemm8(f32x4 (&ACC)[4][2],
    const u16* __restrict__ WH, const u16* __restrict__ WL,
    const u16* A0H, const u16* A0L, const u16* A1H, const u16* A1L, int ASTR,
    int ow, int ln, int qd)
{
  short8 nbh[2], nbl[2];
  if (PF){
    #pragma unroll
    for (int nt = 0; nt < 2; ++nt){ int o = ow + nt*16 + ln;
      nbh[nt] = *(const short8*)(WH + (size_t)o*WS + qd*8);
      nbl[nt] = *(const short8*)(WL + (size_t)o*WS + qd*8);
    }
  }
  #pragma unroll
  for (int c = 0; c < 8; ++c){
    short8 bh[2], bl[2], ah[4], al[4];
    if (PF){
      #pragma unroll
      for (int nt = 0; nt < 2; ++nt){ bh[nt] = nbh[nt]; bl[nt] = nbl[nt]; }
      if (c < 7){
        #pragma unroll
        for (int nt = 0; nt < 2; ++nt){ int o = ow + nt*16 + ln;
          nbh[nt] = *(const short8*)(WH + (size_t)o*WS + (c+1)*32 + qd*8);
          nbl[nt] = *(const short8*)(WL + (size_t)o*WS + (c+1)*32 + qd*8);
        }
      }
    } else {
      #pragma unroll
      for (int nt = 0; nt < 2; ++nt){ int o = ow + nt*16 + ln;
        bh[nt] = *(const short8*)(WH + (size_t)o*WS + c*32 + qd*8);
        bl[nt] = *(const short8*)(WL + (size_t)o*WS + c*32 + qd*8);
      }
    }
    const u16* hs = (c < 4) ? A0H : A1H;
    const u16* ls = (c < 4) ? A0L : A1L;
    int cc = (c < 4) ? c : c - 4;
    #pragma unroll
    for (int mt = 0; mt < 4; ++mt){
      int base = (mt*16 + ln)*ASTR + cc*32 + qd*8;
      ah[mt] = *(const short8*)&hs[base];
      al[mt] = *(const short8*)&ls[base];
    }
    #pragma unroll
    for (int mt = 0; mt < 4; ++mt)
      #pragma unroll
      for (int nt = 0; nt < 2; ++nt)
        ACC[mt][nt] = __builtin_amdgcn_mfma_f32_16x16x32_bf16(ah[mt], bh[nt], ACC[mt][nt], 0, 0, 0);
    #pragma unroll
    for (int mt = 0; mt < 4; ++mt)
      #pragma unroll
      for (int nt = 0; nt < 2; ++nt)
        ACC[mt][nt] = __builtin_amdgcn_mfma_f32_16x16x32_bf16(ah[mt], bl[nt], ACC[mt][nt], 0, 0, 0);
    #pragma unroll
    for (int mt = 0; mt < 4; ++mt)
      #pragma unroll
      for (int nt = 0; nt < 2; ++nt)
        ACC[mt][nt] = __builtin_amdgcn_mfma_f32_16x16x32_bf16(al[mt], bh[nt], ACC[mt][nt], 0, 0, 0);
  }
}

__global__ __launch_bounds__(512, 4) void edge_logits_kernel(
    const float* __restrict__ node_rep, const float* __restrict__ rel_emb,
    const u16* __restrict__ WlH, const u16* __restrict__ WlL,
    const u16* __restrict__ WrH, const u16* __restrict__ WrL,
    const u16* __restrict__ WcH, const u16* __restrict__ WcL,
    const float* __restrict__ bcb,
    const float* __restrict__ Qlt, const float* __restrict__ Qrt,
    const int* __restrict__ idx_i, const int* __restrict__ idx_j, const int* __restrict__ qidx,
    float* __restrict__ logits, u32* __restrict__ segmax, int* __restrict__ qcount)
{
  __shared__ __align__(16) u16 bufA[2*BM*HST];  // Hj -> Hi -> RRhi
  __shared__ __align__(16) u16 bufB[2*BM*HST];  // Rel -> RRlo
  __shared__ int qidS[BM];
  __shared__ float lpart[8][BM];

  u16* HjHi = bufA;  u16* HjLo = bufA + BM*HST;
  u16* ReHi = bufB;  u16* ReLo = bufB + BM*HST;
  u16* RRhi = bufA;  u16* RRlo = bufB;

  const int tid = threadIdx.x;
  const int e0 = blockIdx.x * BM;
  const int lane = tid & 63, w = tid >> 6;
  const int ln = lane & 15, qd = lane >> 4;
  const int ow = w * 32;

  if (tid < BM) qidS[tid] = qidx[e0 + tid];

  // stage Hj + Rel into LDS (hi/lo split); 2048 seg-slots over 512 threads
  #pragma unroll
  for (int it = 0; it < 4; ++it){
    int c = tid + it*512;
    int r = c >> 5, seg = (c & 31) << 2;
    int j = idx_j[e0 + r];
    f32x4 vj = *(const f32x4*)(node_rep + (size_t)j*DD + seg);
    f32x4 vr = *(const f32x4*)(rel_emb + (size_t)(e0 + r)*DD + seg);
    stage4(vj, &HjHi[r*HST + seg], &HjLo[r*HST + seg]);
    stage4(vr, &ReHi[r*HST + seg], &ReLo[r*HST + seg]);
  }
  // pre-gather Hi rows, convert to bf16 hi/lo now (restage = pure LDS writes)
  short4v hpreH[4], hpreL[4];
  #pragma unroll
  for (int it = 0; it < 4; ++it){
    int c = tid + it*512;
    int r = c >> 5, seg = (c & 31) << 2;
    f32x4 v = *(const f32x4*)(node_rep + (size_t)idx_i[e0 + r]*DD + seg);
    cvt4(v, hpreH[it], hpreL[it]);
  }
  __syncthreads();

  // ---- right GEMM: acc = [Hj|Rel] @ Wr^T ----
  f32x4 acc[4][2];
  #pragma unroll
  for (int mt = 0; mt < 4; ++mt)
    #pragma unroll
    for (int nt = 0; nt < 2; ++nt) acc[mt][nt] = (f32x4){0.f,0.f,0.f,0.f};
  gemm8<512, 1>(acc, WrH, WrL, HjHi, HjLo, ReHi, ReLo, HST, ow, ln, qd);
  __syncthreads();   // all waves done reading Hj

  // restage Hi from pre-converted registers into bufA (over Hj)
  #pragma unroll
  for (int it = 0; it < 4; ++it){
    int c = tid + it*512;
    int r = c >> 5, seg = (c & 31) << 2;
    *(short4v*)&HjHi[r*HST + seg] = hpreH[it];
    *(short4v*)&HjLo[r*HST + seg] = hpreL[it];
  }
  __syncthreads();

  // ---- left GEMM: lacc = [Hi|Rel] @ Wl^T ----
  f32x4 lacc[4][2];
  #pragma unroll
  for (int mt = 0; mt < 4; ++mt)
    #pragma unroll
    for (int nt = 0; nt < 2; ++nt) lacc[mt][nt] = (f32x4){0.f,0.f,0.f,0.f};
  gemm8<512, 1>(lacc, WlH, WlL, HjHi, HjLo, ReHi, ReLo, HST, ow, ln, qd);
  __syncthreads();   // Hi/Rel dead; RR may overlay bufA/bufB

  // epilogue: RR = leaky(acc + Qright[qid][col]); split into hi/lo in LDS
  #pragma unroll
  for (int mt = 0; mt < 4; ++mt)
    #pragma unroll
    for (int nt = 0; nt < 2; ++nt){
      int col = ow + nt*16 + ln;
      #pragma unroll
      for (int rg = 0; rg < 4; ++rg){
        int row = mt*16 + qd*4 + rg;
        float v = acc[mt][nt][rg] + Qrt[qidS[row]*OO + col];
        v = lrelu(v);
        u16 hi = f2b(v);
        RRhi[row*RSTc + col] = hi;
        RRlo[row*RSTc + col] = f2b(v - b2f(hi));
      }
    }
  __syncthreads();

  // ---- center GEMM: racc = (RRhi+RRlo) @ Wc^T ----
  f32x4 racc[4][2];
  #pragma unroll
  for (int mt = 0; mt < 4; ++mt)
    #pragma unroll
    for (int nt = 0; nt < 2; ++nt) racc[mt][nt] = (f32x4){0.f,0.f,0.f,0.f};
  gemm8<256, 1>(racc, WcH, WcL, RRhi, RRlo, RRhi + 128, RRlo + 128, RSTc, ow, ln, qd);

  // fused logits dot: sum_o leaky(L) * (R + b_center)
  float bcv[2];
  #pragma unroll
  for (int nt = 0; nt < 2; ++nt) bcv[nt] = bcb[ow + nt*16 + ln];

  float part[4][4];
  #pragma unroll
  for (int mt = 0; mt < 4; ++mt)
    #pragma unroll
    for (int rg = 0; rg < 4; ++rg) part[mt][rg] = 0.f;

  #pragma unroll
  for (int mt = 0; mt < 4; ++mt)
    #pragma unroll
    for (int nt = 0; nt < 2; ++nt){
      int col = ow + nt*16 + ln;
      #pragma unroll
      for (int rg = 0; rg < 4; ++rg){
        int row = mt*16 + qd*4 + rg;
        float lv = lacc[mt][nt][rg] + Qlt[qidS[row]*OO + col];
        lv = lrelu(lv);
        float rv = racc[mt][nt][rg] + bcv[nt];
        part[mt][rg] += lv * rv;
      }
    }

  #pragma unroll
  for (int mt = 0; mt < 4; ++mt)
    #pragma unroll
    for (int rg = 0; rg < 4; ++rg){
      float p = part[mt][rg];
      p += __shfl_xor(p, 1); p += __shfl_xor(p, 2);
      p += __shfl_xor(p, 4); p += __shfl_xor(p, 8);
      if (ln == 0) lpart[w][mt*16 + qd*4 + rg] = p;
    }
  __syncthreads();
  if (tid < BM){
    float lg = lpart[0][tid] + lpart[1][tid] + lpart[2][tid] + lpart[3][tid]
             + lpart[4][tid] + lpart[5][tid] + lpart[6][tid] + lpart[7][tid];
    int e = e0 + tid;
    logits[e] = lg;
    atomicMax(segmax + idx_i[e], fenc(lg));   // fused seg_max_count
    atomicAdd(qcount + qidx[e], 1);
  }
}

// ---------------- K2: segment exp + denom sum ----------------------------------
__global__ void seg_exp_sum_kernel(const float* __restrict__ logits,
    const int* __restrict__ idx_i, const u32* __restrict__ segmax,
    float* __restrict__ ex, float* __restrict__ denom)
{
  int e = blockIdx.x*256 + threadIdx.x; if (e >= NE) return;
  int i = idx_i[e];
  float d = fminf(logits[e] - fdec(segmax[i]), 0.0f);
  float v = expf(d);
  ex[e] = v;
  atomicAdd(denom + i, v);
}

// ---------------- K3: scan of query counts (wave-parallel Hillis-Steele) -------
__global__ __launch_bounds__(128) void scan_kernel(const int* __restrict__ qcount,
                            int* __restrict__ qstart, int* __restrict__ qcursor)
{
  __shared__ int s[NQ];
  int t = threadIdx.x;
  int mine = qcount[t];
  s[t] = mine;
  __syncthreads();
  #pragma unroll
  for (int off = 1; off < NQ; off <<= 1){
    int v = (t >= off) ? s[t - off] : 0;
    __syncthreads();
    s[t] += v;
    __syncthreads();
  }
  int excl = s[t] - mine;
  qstart[t] = excl;
  qcursor[t] = excl;
}

// ---------------- K4: fused attn/target + bucket fill --------------------------
__global__ void attn_bucket_kernel(const float* __restrict__ ex,
    const float* __restrict__ denom, const int* __restrict__ idx_i,
    const float* __restrict__ visited, const int* __restrict__ qidx,
    int* __restrict__ qcursor, int* __restrict__ bucket,
    float* __restrict__ attn, float* __restrict__ target)
{
  int e = blockIdx.x*256 + threadIdx.x; if (e >= NE) return;
  int i = idx_i[e];
  float a = ex[e] / fmaxf(denom[i], 1e-30f);
  attn[e] = a;
  target[e] = a * visited[i];
  int p = atomicAdd(qcursor + qidx[e], 1);
  bucket[p] = e;
}

// ---------------- K5: exact per-group top-k (count-beats, lexsort-stable) ------
#define TOPK_CAP 2560
__global__ __launch_bounds__(1024) void topk_kernel(
    const int* __restrict__ qcount, const int* __restrict__ qstart,
    const int* __restrict__ bucket, const float* __restrict__ target,
    const int* __restrict__ maxe_p, int* __restrict__ keep)
{
  __shared__ float ss[TOPK_CAP];
  __shared__ int   se[TOPK_CAP];
  int q = blockIdx.x;
  int m = qcount[q], start = qstart[q];
  int maxe = *maxe_p;
  if (maxe <= 0 || maxe > (1 << 30)){
    float f = __int_as_float(maxe);
    if (f > 0.0f && f < 1.0e9f) maxe = (int)f;
  }
  int tid = threadIdx.x;
  if (m <= maxe){
    for (int i = tid; i < m; i += 1024) keep[bucket[start + i]] = 1;
    return;
  }
  if (m <= TOPK_CAP){
    for (int i = tid; i < m; i += 1024){
      int e = bucket[start + i]; ss[i] = target[e]; se[i] = e;
    }
    __syncthreads();
    for (int i = tid; i < m; i += 1024){
      float s = ss[i]; int eid = se[i]; int cnt = 0;
      for (int j = 0; j < m; ++j){
        float sj = ss[j]; int ej = se[j];
        cnt += (sj > s) || (sj == s && ej < eid);
      }
      keep[eid] = (cnt < maxe) ? 1 : 0;
    }
  } else {
    for (int i = tid; i < m; i += 1024){
      int eid = bucket[start + i]; float s = target[eid]; int cnt = 0;
      for (int j = 0; j < m; ++j){
        int ej = bucket[start + j]; float sj = target[ej];
        cnt += (sj > s) || (sj == s && ej < eid);
      }
      keep[eid] = (cnt < maxe) ? 1 : 0;
    }
  }
}

// ---------------- K5b: merged scatter: score + attn-weighted hi -----------------
__global__ __launch_bounds__(256) void edge_scatter_kernel(
    const int* __restrict__ keep, const float* __restrict__ attn,
    const float* __restrict__ target,
    const int* __restrict__ idx_i, const int* __restrict__ idx_j,
    const float* __restrict__ node_rep,
    float* __restrict__ out_score, float* __restrict__ agg)
{
  int wid = (blockIdx.x * 256 + threadIdx.x) >> 6;
  if (wid >= NE) return;
  if (!keep[wid]) return;                 // wave-uniform
  int lane = threadIdx.x & 63;
  int ii = idx_i[wid], jj = idx_j[wid];
  float a = attn[wid];
  if (lane == 0) atomicAdd(out_score + jj, target[wid]);
  float h0 = node_rep[(size_t)ii*DD + lane];
  float h1 = node_rep[(size_t)ii*DD + 64 + lane];
  atomicAdd(agg + (size_t)jj*DD + lane,      a*h0);
  atomicAdd(agg + (size_t)jj*DD + 64 + lane, a*h1);
}

// ---------------- K6: out_rep = leaky((node_rep+agg) @ Wstep^T + bstep), MFMA ---
// agg aliases out_rep: each block reads its 64 rows into LDS (before barrier),
// then overwrites the same rows. Rows are disjoint across blocks -> safe.
__global__ __launch_bounds__(256) void final_mfma_kernel(
    const float* __restrict__ node_rep, const float* __restrict__ aggc,
    const u16* __restrict__ WsH, const u16* __restrict__ WsL,
    const float* __restrict__ bstep, float* __restrict__ out_rep)
{
  __shared__ __align__(16) u16 Ahi[64*HST];
  __shared__ __align__(16) u16 Alo[64*HST];
  const int tid = threadIdx.x;
  const int m0 = blockIdx.x * 64;

  for (int c = tid; c < 64*32; c += 256){
    int r = c >> 5, seg = (c & 31) << 2;
    int m = m0 + r;
    float v[4];
    if (m < N_NODES){
      const float* nr = node_rep + (size_t)m*DD + seg;
      const float* ag = aggc + (size_t)m*DD + seg;
      #pragma unroll
      for (int i = 0; i < 4; ++i) v[i] = nr[i] + ag[i];
    } else {
      #pragma unroll
      for (int i = 0; i < 4; ++i) v[i] = 0.f;
    }
    short4v h4, l4;
    #pragma unroll
    for (int i = 0; i < 4; ++i){
      u16 h = f2b(v[i]); h4[i] = (short)h; l4[i] = (short)f2b(v[i] - b2f(h));
    }
    *(short4v*)&Ahi[r*HST + seg] = h4;
    *(short4v*)&Alo[r*HST + seg] = l4;
  }
  __syncthreads();

  const int lane = tid & 63, w = tid >> 6;
  const int ln = lane & 15, qd = lane >> 4;
  const int ow = w * 32;

  short8 bh[2][4], bl[2][4];
  #pragma unroll
  for (int nt = 0; nt < 2; ++nt)
    #pragma unroll
    for (int c = 0; c < 4; ++c){
      int o = ow + nt*16 + ln;
      bh[nt][c] = *(const short8*)(WsH + (size_t)o*DD + c*32 + qd*8);
      bl[nt][c] = *(const short8*)(WsL + (size_t)o*DD + c*32 + qd*8);
    }

  f32x4 acc[4][2];
  #pragma unroll
  for (int mt = 0; mt < 4; ++mt)
    #pragma unroll
    for (int nt = 0; nt < 2; ++nt) acc[mt][nt] = (f32x4){0.f,0.f,0.f,0.f};

  #pragma unroll
  for (int mt = 0; mt < 4; ++mt)
    #pragma unroll
    for (int c = 0; c < 4; ++c){
      int base = (mt*16 + ln)*HST + c*32 + qd*8;
      short8 ah = *(const short8*)&Ahi[base];
      short8 al = *(const short8*)&Alo[base];
      #pragma unroll
      for (int nt = 0; nt < 2; ++nt){
        acc[mt][nt] = __builtin_amdgcn_mfma_f32_16x16x32_bf16(ah, bh[nt][c], acc[mt][nt], 0, 0, 0);
        acc[mt][nt] = __builtin_amdgcn_mfma_f32_16x16x32_bf16(ah, bl[nt][c], acc[mt][nt], 0, 0, 0);
        acc[mt][nt] = __builtin_amdgcn_mfma_f32_16x16x32_bf16(al, bh[nt][c], acc[mt][nt], 0, 0, 0);
      }
    }

  #pragma unroll
  for (int mt = 0; mt < 4; ++mt)
    #pragma unroll
    for (int nt = 0; nt < 2; ++nt){
      int col = ow + nt*16 + ln;
      float bs = bstep[col];
      #pragma unroll
      for (int rg = 0; rg < 4; ++rg){
        int m = m0 + mt*16 + qd*4 + rg;
        if (m < N_NODES)
          out_rep[(size_t)m*DD + col] = lrelu(acc[mt][nt][rg] + bs);
      }
    }
}

// ---------------- host ---------------------------------------------------------
extern "C" void kernel_launch(void* const* d_in, const int* in_sizes, int n_in,
                              void* d_out, int out_size, void* d_ws, size_t ws_size,
                              hipStream_t stream)
{
  const float* visited  = (const float*)d_in[0];
  const float* node_rep = (const float*)d_in[1];
  const float* qsrc     = (const float*)d_in[2];
  const float* qrel     = (const float*)d_in[3];
  const float* rel_emb  = (const float*)d_in[4];
  const float* Wl       = (const float*)d_in[5];
  const float* bl       = (const float*)d_in[6];
  const float* Wr       = (const float*)d_in[7];
  const float* br       = (const float*)d_in[8];
  const float* Wc       = (const float*)d_in[9];
  const float* bcb      = (const float*)d_in[10];
  const float* Wstep    = (const float*)d_in[11];
  const float* bstep    = (const float*)d_in[12];
  const int* qidx       = (const int*)d_in[13];
  const int* idx_i      = (const int*)d_in[14];
  const int* idx_j      = (const int*)d_in[15];
  const int* maxe       = (const int*)d_in[16];

  // ---- workspace layout (no agg buffer: agg aliases out_rep) ----
  char* wp = (char*)d_ws;
  size_t used = 0;
  auto alloc = [&](size_t bytes)->char*{
    size_t pad = (bytes + 255) & ~(size_t)255;
    char* p = wp + used; used += pad; return p;
  };
  float* Qlt    = (float*)alloc((size_t)NQ*OO*4);
  float* Qrt    = (float*)alloc((size_t)NQ*OO*4);
  float* logits = (float*)alloc((size_t)NE*4);
  float* ex     = (float*)alloc((size_t)NE*4);
  float* attn   = (float*)alloc((size_t)NE*4);
  float* target = (float*)alloc((size_t)NE*4);
  u32*   segmax = (u32*)  alloc((size_t)N_NODES*4);
  float* denom  = (float*)alloc((size_t)N_NODES*4);
  int*   qcount = (int*)  alloc((size_t)NQ*4);
  int*   qstart = (int*)  alloc((size_t)NQ*4);
  int*   qcursor= (int*)  alloc((size_t)NQ*4);
  int*   bucket = (int*)  alloc((size_t)NE*4);
  int*   keep   = (int*)  alloc((size_t)NE*4);
  u16* WlH = (u16*)alloc((size_t)256*512*2); u16* WlL = (u16*)alloc((size_t)256*512*2);
  u16* WrH = (u16*)alloc((size_t)256*512*2); u16* WrL = (u16*)alloc((size_t)256*512*2);
  u16* WcH = (u16*)alloc((size_t)256*256*2); u16* WcL = (u16*)alloc((size_t)256*256*2);
  u16* WsH = (u16*)alloc((size_t)128*128*2); u16* WsL = (u16*)alloc((size_t)128*128*2);
  (void)ws_size; (void)in_sizes; (void)n_in; (void)out_size;

  float* out_score = (float*)d_out;               // f32 outputs
  float* out_rep   = (float*)d_out + N_NODES;     // also serves as agg accumulator

  hipMemsetAsync(d_out, 0, ((size_t)N_NODES + (size_t)N_NODES*DD)*4, stream);
  hipMemsetAsync(segmax, 0, (size_t)N_NODES*4, stream);
  hipMemsetAsync(denom,  0, (size_t)N_NODES*4, stream);
  hipMemsetAsync(qcount, 0, (size_t)NQ*4,      stream);
  hipMemsetAsync(keep,   0, (size_t)NE*4,      stream);

  {
    int n_all = SPL_N1 + SPL_N2 + SPL_N3 + SPL_N4;
    split_all_kernel<<<(n_all + 255)/256, 256, 0, stream>>>(Wl, Wr, Wc, Wstep,
        WlH, WlL, WrH, WrL, WcH, WcL, WsH, WsL);
  }

  qtable_kernel<<<256, 256, 0, stream>>>(qsrc, qrel, Wl, bl, Wr, br, Qlt, Qrt);

  edge_logits_kernel<<<NE/BM, 512, 0, stream>>>(node_rep, rel_emb,
      WlH, WlL, WrH, WrL, WcH, WcL, bcb, Qlt, Qrt, idx_i, idx_j, qidx,
      logits, segmax, qcount);

  seg_exp_sum_kernel<<<NE/256, 256, 0, stream>>>(logits, idx_i, segmax, ex, denom);
  scan_kernel<<<1, 128, 0, stream>>>(qcount, qstart, qcursor);
  attn_bucket_kernel<<<NE/256, 256, 0, stream>>>(ex, denom, idx_i, visited, qidx,
                                                 qcursor, bucket, attn, target);
  topk_kernel<<<NQ, 1024, 0, stream>>>(qcount, qstart, bucket, target, maxe, keep);

  edge_scatter_kernel<<<NE/4, 256, 0, stream>>>(keep, attn, target, idx_i, idx_j,
                                                node_rep, out_score, out_rep);
  final_mfma_kernel<<<(N_NODES + 63)/64, 256, 0, stream>>>(node_rep, out_rep,
                                               WsH, WsL, bstep, out_rep);
}